// Round 6
// baseline (141.267 us; speedup 1.0000x reference)
//
#include <hip/hip_runtime.h>
#include <array>

// Problem constants (reference: H=64, M=N=128, k=9, w=3)
constexpr int HZ   = 64;
constexpr int NN   = 128;
constexpr int P    = HZ * NN * NN;    // 1,048,576 voxels
constexpr int KSEL = 9;
constexpr int NCOL = 27;              // 3x3x3 window
constexpr int ST   = 12;              // row stride in floats (48 B, float4-aligned)
// Row layout (12 floats): [0..8] sorted top-9 values, [9] code_lo (6x5b),
// [10] code_hi (3x5b), [11] pad/garbage.

// ---------------------------------------------------------------------------
// Batcher merge-exchange network for n=27 (Knuth 5.2.2M), then constexpr
// dead-CE pruning: keep a compare-exchange iff its outputs can reach
// positions 0..8 (we only need the smallest 9, in order). 155 -> ~120 CEs.
// ---------------------------------------------------------------------------
constexpr int compute_nce(int n) {
  int t = 0; while ((1 << t) < n) ++t;
  int cnt = 0;
  for (int p = 1 << (t - 1); p > 0; p >>= 1) {
    int q = 1 << (t - 1), r = 0, d = p;
    while (true) {
      for (int i = 0; i < n - d; ++i)
        if ((i & p) == r) ++cnt;
      if (q == p) break;
      d = q - p; r = p; q >>= 1;
    }
  }
  return cnt;
}
constexpr int NCE_FULL = compute_nce(NCOL);   // 155

struct CEPair { unsigned char a, b; };
constexpr std::array<CEPair, NCE_FULL> make_net() {
  std::array<CEPair, NCE_FULL> net{};
  int t = 0; while ((1 << t) < NCOL) ++t;
  int k = 0;
  for (int p = 1 << (t - 1); p > 0; p >>= 1) {
    int q = 1 << (t - 1), r = 0, d = p;
    while (true) {
      for (int i = 0; i < NCOL - d; ++i)
        if ((i & p) == r) {
          net[k].a = (unsigned char)i;
          net[k].b = (unsigned char)(i + d);
          ++k;
        }
      if (q == p) break;
      d = q - p; r = p; q >>= 1;
    }
  }
  return net;
}
constexpr auto FULLNET = make_net();

constexpr int count_pruned() {
  bool needed[NCOL] = {};
  for (int i = 0; i < KSEL; ++i) needed[i] = true;
  int cnt = 0;
  for (int e = NCE_FULL - 1; e >= 0; --e) {
    const int a = FULLNET[e].a, b = FULLNET[e].b;
    if (needed[a] || needed[b]) { needed[a] = true; needed[b] = true; ++cnt; }
  }
  return cnt;
}
constexpr int NCE = count_pruned();

constexpr std::array<CEPair, NCE> make_pruned() {
  bool needed[NCOL] = {};
  for (int i = 0; i < KSEL; ++i) needed[i] = true;
  std::array<bool, NCE_FULL> keep{};
  for (int e = NCE_FULL - 1; e >= 0; --e) {
    const int a = FULLNET[e].a, b = FULLNET[e].b;
    if (needed[a] || needed[b]) { keep[e] = true; needed[a] = true; needed[b] = true; }
  }
  std::array<CEPair, NCE> out{};
  int k = 0;
  for (int e = 0; e < NCE_FULL; ++e) if (keep[e]) out[k++] = FULLNET[e];
  return out;
}
constexpr auto NET = make_pruned();

// ---------------------------------------------------------------------------
// Pass 1 (R6): stable top-9 of 27 neighbors by |v - center| via the pruned
// sorting network on u64 keys (distbits<<5 | col); ties strict via col LSBs
// -> exact NumPy stable order. Winners exit in rank order.
// ---------------------------------------------------------------------------
__global__ __launch_bounds__(256) void topk5(
    const float* __restrict__ anat,
    float* __restrict__ rows) {
  __shared__ float tile[12 * 128];   // 6 KB: [zi 0..2][yrow 0..3][x 0..127]
  __shared__ float lrow[256 * ST];   // 12 KB output staging
  const int tid = threadIdx.x;
  const int ib  = blockIdx.x << 8;
  const int x   = tid & (NN - 1);
  const int yl  = tid >> 7;
  const int y0  = (ib >> 7) & (NN - 1);
  const int z   = ib >> 14;

  // Stage halo: 12 rows x 32 float4 = 384 float4.
  #pragma unroll
  for (int s = 0; s < 2; ++s) {
    const int q = tid + s * 256;
    if (q < 384) {
      const int row = q >> 5;
      const int col = q & 31;
      const int zz = (z + (row >> 2) - 1) & (HZ - 1);
      const int yy = (y0 + (row & 3) - 1) & (NN - 1);
      ((float4*)tile)[q] =
          *(const float4*)(anat + ((zz << 14) | (yy << 7) | (col << 2)));
    }
  }
  __syncthreads();

  const int xa[3] = {(x + NN - 1) & (NN - 1), x, (x + 1) & (NN - 1)};
  const float center = tile[512 + (yl + 1) * 128 + x];   // col 13

  // Pack keys: non-negative float bits are unsigned-order-isomorphic.
  unsigned long long key[NCOL];
  #pragma unroll
  for (int c = 0; c < NCOL; ++c) {
    const int zi = c / 9, yi = (c / 3) % 3;
    const float v = tile[zi * 512 + (yl + yi) * 128 + xa[c % 3]];
    const unsigned db = __float_as_uint(v - center) & 0x7fffffffu;
    key[c] = ((unsigned long long)db << 5) | (unsigned)c;
  }

  // Pruned sorting network (~120 CEs, 5 VALU each).
  #pragma unroll
  for (int e = 0; e < NCE; ++e) {
    const int a = NET[e].a, b = NET[e].b;
    const unsigned long long xk = key[a], yk = key[b];
    const bool sw = xk > yk;
    key[a] = sw ? yk : xk;
    key[b] = sw ? xk : yk;
  }

  // Winners in rank order: re-read values by col, pack codes.
  float* myrow = &lrow[tid * ST];
  unsigned lo = 0, hi = 0;
  #pragma unroll
  for (int s = 0; s < KSEL; ++s) {
    const unsigned c = (unsigned)(key[s] & 31u);
    const unsigned czi = (c * 57u) >> 9;          // c / 9  (exact for c < 32)
    const unsigned rem = c - 9u * czi;
    const unsigned cyi = (rem * 11u) >> 5;        // rem / 3 (exact for rem < 9)
    const unsigned cxi = rem - 3u * cyi;
    myrow[s] = tile[czi * 512 + (yl + cyi) * 128 + xa[cxi]];
    if (s < 6) lo |= c << (5 * s);
    else       hi |= c << (5 * (s - 6));
  }
  myrow[9]  = __uint_as_float(lo);
  myrow[10] = __uint_as_float(hi);

  __syncthreads();

  // Coalesced writeback: 3 x 256 x float4 = 12 KB, full line coverage.
  float4* g = (float4*)(rows + (size_t)blockIdx.x * 256 * ST);
  const float4* l4 = (const float4*)lrow;
  #pragma unroll
  for (int rnd = 0; rnd < 3; ++rnd) g[rnd * 256 + tid] = l4[rnd * 256 + tid];
}

// ---------------------------------------------------------------------------
// Pass 2 (R6): 8y x 32x core tile (256 voxels), halo = 3z x 10y x 34x =
// 1020 rows x 48 B = 48.96 KB LDS -> 3 blocks/CU (occupancy 25%->37.5%) and
// halo amplification 6.0x -> 3.98x (302->200 MB of L2 staging traffic).
// Row stride 12 words keeps neighbor gathers conflict-free ds_read_b128.
// XCD swizzle: 512-block z-slab per XCD, inner sweep 8z x 16y x 4x.
// ---------------------------------------------------------------------------
constexpr int TY = 10;   // tile y rows (8 core + 2 halo)
constexpr int TX = 34;   // tile x cols (32 core + 2 halo)
constexpr int TROWS = 3 * TY * TX;   // 1020

__global__ __launch_bounds__(256) void weights5(
    const float* __restrict__ rows,
    const float* __restrict__ ksig,
    float* __restrict__ out) {
  __shared__ float tile[TROWS * ST];   // 48960 B; reused for output staging
  const int tid = threadIdx.x;

  const int blk = blockIdx.x;
  const int swz = ((blk & 7) << 9) | (blk >> 3);   // 8 XCDs x 512-slab
  const int z    = swz >> 6;            // 0..63
  const int rest = swz & 63;            // 16y-tiles x 4x-tiles
  const int y0   = ((rest >> 2) & 15) << 3;
  const int x0   = (rest & 3) << 5;
  const int xl   = tid & 31;
  const int yl   = tid >> 5;            // 0..7

  // ---- Stage halo: 1020 rows x 3 float4 = 3060 float4 (12/thread). ----
  const float4* rows4 = (const float4*)rows;
  float4* t4 = (float4*)tile;
  #pragma unroll
  for (int s = 0; s < 12; ++s) {
    const unsigned q = (unsigned)(s * 256 + tid);
    if (q < 3060u) {
      const unsigned p   = q / 102u;       // (zi,yi) pair 0..29
      const unsigned rem = q - p * 102u;
      const unsigned r   = rem / 3u;       // x-row within pair 0..33
      const unsigned c   = rem - 3u * r;   // float4 within row
      const int zi = (int)(p / 10u), yi = (int)(p - 10u * (p / 10u));
      const int zz = (z + zi - 1) & (HZ - 1);
      const int yy = (y0 + yi - 1) & (NN - 1);
      const int xg = (x0 - 1 + (int)r) & (NN - 1);
      t4[q] = rows4[(size_t)((zz << 14) | (yy << 7) | xg) * 3 + c];
    }
  }
  __syncthreads();

  // ---- Own row: zi=1, yi=yl+1, xt=xl+1. ----
  const int rho_own = (TY + (yl + 1)) * TX + (xl + 1);
  const float4 w0 = t4[rho_own * 3], w1 = t4[rho_own * 3 + 1], w2 = t4[rho_own * 3 + 2];
  const float ws[KSEL] = {w0.x, w0.y, w0.z, w0.w, w1.x, w1.y, w1.z, w1.w, w2.x};
  const unsigned lo = __float_as_uint(w2.y);
  const unsigned hi = __float_as_uint(w2.z);

  // sigma with ddof=1 (two-pass, matches jnp.std)
  float mean = 0.f;
  #pragma unroll
  for (int l = 0; l < KSEL; ++l) mean += ws[l];
  mean *= (1.0f / 9.0f);
  float var = 0.f;
  #pragma unroll
  for (int l = 0; l < KSEL; ++l) { const float t = ws[l] - mean; var += t * t; }
  var *= (1.0f / 8.0f);
  const float sigma = sqrtf(var);

  const float ks = ksig[0];
  const float inv = (sigma == 0.f) ? 0.f : 1.0f / (2.0f * ks * ks * sigma * sigma);

  float logit[KSEL];
  #pragma unroll
  for (int j = 0; j < KSEL; ++j) {
    const unsigned c = (j < 6) ? ((lo >> (5 * j)) & 31u)
                               : ((hi >> (5 * (j - 6))) & 31u);
    const unsigned czi = (c * 57u) >> 9;          // c / 9
    const unsigned rem = c - 9u * czi;
    const unsigned cyi = (rem * 11u) >> 5;        // rem / 3
    const unsigned cxi = rem - 3u * cyi;
    // tile row: zi=czi, yi=yl+cyi (0..9), xt=xl+cxi (0..33)
    const int rho = (int)czi * (TY * TX) + (yl + (int)cyi) * TX + (xl + (int)cxi);
    const float4 n0 = t4[rho * 3], n1 = t4[rho * 3 + 1], n2 = t4[rho * 3 + 2];
    const float nv[KSEL] = {n0.x, n0.y, n0.z, n0.w, n1.x, n1.y, n1.z, n1.w, n2.x};
    float s = 0.f;
    #pragma unroll
    for (int l = 0; l < KSEL; ++l) {
      const float t = ws[l] - nv[l] + 1e-6f;
      s = fmaf(t, t, s);
    }
    logit[j] = -s * inv;
  }

  // softmax over the 9 logits
  float mx = logit[0];
  #pragma unroll
  for (int j = 1; j < KSEL; ++j) mx = fmaxf(mx, logit[j]);
  float sum = 0.f;
  float e[KSEL];
  #pragma unroll
  for (int j = 0; j < KSEL; ++j) { e[j] = __expf(logit[j] - mx); sum += e[j]; }
  const float rs = 1.0f / sum;

  // ---- Reuse tile front as output staging. ----
  __syncthreads();
  #pragma unroll
  for (int j = 0; j < KSEL; ++j) tile[tid * KSEL + j] = e[j] * rs;
  __syncthreads();

  // 8 y-rows x 72 float4 each = 576 float4; row r starts at voxel
  // vb=(z,y0+r,x0), f4 dst index = (vb>>2)*9 + f (vb multiple of 32).
  #pragma unroll
  for (int s = 0; s < 3; ++s) {
    const unsigned q = (unsigned)(s * 256 + tid);
    if (q < 576u) {
      const unsigned row = q / 72u;
      const unsigned f   = q - row * 72u;
      const unsigned vb  = (unsigned)((z << 14) | ((y0 + (int)row) << 7) | x0);
      ((float4*)out)[(size_t)(vb >> 2) * 9 + f] = t4[row * 72 + f];
    }
  }
}

// ---------------------------------------------------------------------------
// d_in: [0] input (P floats), [1] ksigma (1 float), [2] k (int), [3] w (int)
// d_ws: row array, P * 12 floats = 48 MB
// ---------------------------------------------------------------------------
extern "C" void kernel_launch(void* const* d_in, const int* in_sizes, int n_in,
                              void* d_out, int out_size, void* d_ws, size_t ws_size,
                              hipStream_t stream) {
  const float* anat = (const float*)d_in[0];
  const float* ksig = (const float*)d_in[1];
  float* rows = (float*)d_ws;

  const int blocks = P / 256;
  topk5<<<blocks, 256, 0, stream>>>(anat, rows);
  weights5<<<blocks, 256, 0, stream>>>(rows, ksig, (float*)d_out);
}

// Round 7
// 131.062 us; speedup vs baseline: 1.0779x; 1.0779x over previous
//
#include <hip/hip_runtime.h>
#include <hip/hip_fp16.h>
#include <array>

// Problem constants (reference: H=64, M=N=128, k=9, w=3)
constexpr int HZ   = 64;
constexpr int NN   = 128;
constexpr int P    = HZ * NN * NN;    // 1,048,576 voxels
constexpr int KSEL = 9;
constexpr int NCOL = 27;              // 3x3x3 window
// fp16 row layout, 8 dwords (32 B): d0=h0h1 d1=h2h3 d2=h4h5 d3=h6h7
// d4=h8 d5=code_lo(6x5b) d6=code_hi(3x5b) d7=pad
constexpr int STD  = 8;               // row stride in dwords

// ---------------------------------------------------------------------------
// Batcher merge-exchange network for n=27 (Knuth 5.2.2M) + backward dead-CE
// pruning to outputs 0..8.
// ---------------------------------------------------------------------------
constexpr int compute_nce(int n) {
  int t = 0; while ((1 << t) < n) ++t;
  int cnt = 0;
  for (int p = 1 << (t - 1); p > 0; p >>= 1) {
    int q = 1 << (t - 1), r = 0, d = p;
    while (true) {
      for (int i = 0; i < n - d; ++i)
        if ((i & p) == r) ++cnt;
      if (q == p) break;
      d = q - p; r = p; q >>= 1;
    }
  }
  return cnt;
}
constexpr int NCE_FULL = compute_nce(NCOL);   // 155

struct CEPair { unsigned char a, b; };
constexpr std::array<CEPair, NCE_FULL> make_net() {
  std::array<CEPair, NCE_FULL> net{};
  int t = 0; while ((1 << t) < NCOL) ++t;
  int k = 0;
  for (int p = 1 << (t - 1); p > 0; p >>= 1) {
    int q = 1 << (t - 1), r = 0, d = p;
    while (true) {
      for (int i = 0; i < NCOL - d; ++i)
        if ((i & p) == r) {
          net[k].a = (unsigned char)i;
          net[k].b = (unsigned char)(i + d);
          ++k;
        }
      if (q == p) break;
      d = q - p; r = p; q >>= 1;
    }
  }
  return net;
}
constexpr auto FULLNET = make_net();

constexpr int count_pruned() {
  bool needed[NCOL] = {};
  for (int i = 0; i < KSEL; ++i) needed[i] = true;
  int cnt = 0;
  for (int e = NCE_FULL - 1; e >= 0; --e) {
    const int a = FULLNET[e].a, b = FULLNET[e].b;
    if (needed[a] || needed[b]) { needed[a] = true; needed[b] = true; ++cnt; }
  }
  return cnt;
}
constexpr int NCE = count_pruned();

constexpr std::array<CEPair, NCE> make_pruned() {
  bool needed[NCOL] = {};
  for (int i = 0; i < KSEL; ++i) needed[i] = true;
  std::array<bool, NCE_FULL> keep{};
  for (int e = NCE_FULL - 1; e >= 0; --e) {
    const int a = FULLNET[e].a, b = FULLNET[e].b;
    if (needed[a] || needed[b]) { keep[e] = true; needed[a] = true; needed[b] = true; }
  }
  std::array<CEPair, NCE> out{};
  int k = 0;
  for (int e = 0; e < NCE_FULL; ++e) if (keep[e]) out[k++] = FULLNET[e];
  return out;
}
constexpr auto NET = make_pruned();

// ---------------------------------------------------------------------------
// Pass 1 (R7): stable top-9 via sorting network on u64 keys
//   key = db(31b) << 33 | col(5b) << 28 | (vbits >> 4)
// Order = (db, col) exactly (cols distinct -> v-bits never decide a tie) ->
// exact NumPy stable order. Value rides in the key: epilogue needs no LDS
// re-reads. Rows written as fp16 (9 halfs + 2 code dwords = 32 B).
// ---------------------------------------------------------------------------
__global__ __launch_bounds__(256) void topk6(
    const float* __restrict__ anat,
    unsigned* __restrict__ rows) {
  __shared__ float tile[12 * 128];      // 6 KB halo: [zi 0..2][yrow 0..3][x]
  __shared__ unsigned lrow[256 * STD];  // 8 KB output staging
  const int tid = threadIdx.x;
  const int ib  = blockIdx.x << 8;
  const int x   = tid & (NN - 1);
  const int yl  = tid >> 7;
  const int y0  = (ib >> 7) & (NN - 1);
  const int z   = ib >> 14;

  // Stage halo: 12 rows x 32 float4 = 384 float4.
  #pragma unroll
  for (int s = 0; s < 2; ++s) {
    const int q = tid + s * 256;
    if (q < 384) {
      const int row = q >> 5;
      const int col = q & 31;
      const int zz = (z + (row >> 2) - 1) & (HZ - 1);
      const int yy = (y0 + (row & 3) - 1) & (NN - 1);
      ((float4*)tile)[q] =
          *(const float4*)(anat + ((zz << 14) | (yy << 7) | (col << 2)));
    }
  }
  __syncthreads();

  const int xa[3] = {(x + NN - 1) & (NN - 1), x, (x + 1) & (NN - 1)};
  const float center = tile[512 + (yl + 1) * 128 + x];   // col 13

  unsigned long long key[NCOL];
  #pragma unroll
  for (int c = 0; c < NCOL; ++c) {
    const int zi = c / 9, yi = (c / 3) % 3;
    const float v = tile[zi * 512 + (yl + yi) * 128 + xa[c % 3]];
    const unsigned vb = __float_as_uint(v);
    const unsigned db = __float_as_uint(v - center) & 0x7fffffffu;
    const unsigned hi32 = (db << 1) | ((unsigned)c >> 4);
    const unsigned lo32 = ((unsigned)c << 28) | (vb >> 4);
    key[c] = ((unsigned long long)hi32 << 32) | lo32;
  }

  // Pruned sorting network (u64 CEs).
  #pragma unroll
  for (int e = 0; e < NCE; ++e) {
    const int a = NET[e].a, b = NET[e].b;
    const unsigned long long xk = key[a], yk = key[b];
    const bool sw = xk > yk;
    key[a] = sw ? yk : xk;
    key[b] = sw ? xk : yk;
  }

  // Epilogue: extract col + value (top-28 bits, <=1 ulp fp16 effect), pack.
  unsigned d[5] = {0, 0, 0, 0, 0};
  unsigned lo = 0, hi = 0;
  #pragma unroll
  for (int s = 0; s < KSEL; ++s) {
    const unsigned c  = (unsigned)(key[s] >> 28) & 31u;
    const unsigned vb = ((unsigned)key[s] & 0x0fffffffu) << 4;
    const ushort hb = __half_as_ushort(__float2half(__uint_as_float(vb)));
    d[s >> 1] |= (unsigned)hb << ((s & 1) * 16);
    if (s < 6) lo |= c << (5 * s);
    else       hi |= c << (5 * (s - 6));
  }

  unsigned* myrow = &lrow[tid * STD];
  ((uint4*)myrow)[0] = make_uint4(d[0], d[1], d[2], d[3]);
  ((uint4*)myrow)[1] = make_uint4(d[4], lo, hi, 0u);

  __syncthreads();

  // Coalesced writeback: 2 x 256 x uint4 = 8 KB, full line coverage.
  uint4* g = (uint4*)(rows + (size_t)blockIdx.x * 256 * STD);
  const uint4* l4 = (const uint4*)lrow;
  g[tid]       = l4[tid];
  g[256 + tid] = l4[256 + tid];
}

// ---------------------------------------------------------------------------
// Pass 2 (R7): 8y x 32x core tile; halo = 3z x 10y x 34x = 1020 fp16 rows x
// 32 B = 32.6 KB LDS -> 4 blocks/CU. Staging traffic 133 MB (was 200), and
// the 32 MB rows array is ~L2-resident per XCD slab (4.19 MB vs 4 MB L2).
// 20 ds_read_b128 per thread (was 30).
// ---------------------------------------------------------------------------
constexpr int TY = 10;
constexpr int TX = 34;
constexpr int TROWS = 3 * TY * TX;   // 1020

__device__ inline void unpack9(const uint4 a, const uint4 b, float* f) {
  f[0] = __half2float(__ushort_as_half((ushort)(a.x & 0xffffu)));
  f[1] = __half2float(__ushort_as_half((ushort)(a.x >> 16)));
  f[2] = __half2float(__ushort_as_half((ushort)(a.y & 0xffffu)));
  f[3] = __half2float(__ushort_as_half((ushort)(a.y >> 16)));
  f[4] = __half2float(__ushort_as_half((ushort)(a.z & 0xffffu)));
  f[5] = __half2float(__ushort_as_half((ushort)(a.z >> 16)));
  f[6] = __half2float(__ushort_as_half((ushort)(a.w & 0xffffu)));
  f[7] = __half2float(__ushort_as_half((ushort)(a.w >> 16)));
  f[8] = __half2float(__ushort_as_half((ushort)(b.x & 0xffffu)));
}

__global__ __launch_bounds__(256) void weights6(
    const unsigned* __restrict__ rows,
    const float* __restrict__ ksig,
    float* __restrict__ out) {
  __shared__ unsigned tile[TROWS * STD];   // 32640 B; reused for out staging
  const int tid = threadIdx.x;

  const int blk = blockIdx.x;
  const int swz = ((blk & 7) << 9) | (blk >> 3);   // 8 XCDs x 512-slab
  const int z    = swz >> 6;
  const int rest = swz & 63;
  const int y0   = ((rest >> 2) & 15) << 3;
  const int x0   = (rest & 3) << 5;
  const int xl   = tid & 31;
  const int yl   = tid >> 5;

  // ---- Stage halo: 1020 rows x 2 uint4 = 2040 uint4 (8/thread). ----
  const uint4* rows4 = (const uint4*)rows;
  uint4* t4 = (uint4*)tile;
  #pragma unroll
  for (int s = 0; s < 8; ++s) {
    const unsigned q = (unsigned)(s * 256 + tid);
    if (q < 2040u) {
      const unsigned p   = q / 68u;        // (zi,yi) pair 0..29
      const unsigned rem = q - p * 68u;
      const unsigned r   = rem >> 1;       // x-row within pair 0..33
      const unsigned c   = rem & 1u;
      const unsigned pz  = p / 10u;
      const int zi = (int)pz, yi = (int)(p - 10u * pz);
      const int zz = (z + zi - 1) & (HZ - 1);
      const int yy = (y0 + yi - 1) & (NN - 1);
      const int xg = (x0 - 1 + (int)r) & (NN - 1);
      t4[q] = rows4[(size_t)((zz << 14) | (yy << 7) | xg) * 2 + c];
    }
  }
  __syncthreads();

  // ---- Own row: zi=1, yi=yl+1, xt=xl+1. ----
  const int rho_own = (TY + (yl + 1)) * TX + (xl + 1);
  const uint4 u0 = t4[rho_own * 2], u1 = t4[rho_own * 2 + 1];
  float ws[KSEL];
  unpack9(u0, u1, ws);
  const unsigned lo = u1.y;
  const unsigned hi = u1.z;

  // sigma with ddof=1 (two-pass, matches jnp.std)
  float mean = 0.f;
  #pragma unroll
  for (int l = 0; l < KSEL; ++l) mean += ws[l];
  mean *= (1.0f / 9.0f);
  float var = 0.f;
  #pragma unroll
  for (int l = 0; l < KSEL; ++l) { const float t = ws[l] - mean; var += t * t; }
  var *= (1.0f / 8.0f);
  const float sigma = sqrtf(var);

  const float ks = ksig[0];
  const float inv = (sigma == 0.f) ? 0.f : 1.0f / (2.0f * ks * ks * sigma * sigma);

  float logit[KSEL];
  #pragma unroll
  for (int j = 0; j < KSEL; ++j) {
    const unsigned c = (j < 6) ? ((lo >> (5 * j)) & 31u)
                               : ((hi >> (5 * (j - 6))) & 31u);
    const unsigned czi = (c * 57u) >> 9;          // c / 9
    const unsigned rem = c - 9u * czi;
    const unsigned cyi = (rem * 11u) >> 5;        // rem / 3
    const unsigned cxi = rem - 3u * cyi;
    const int rho = (int)czi * (TY * TX) + (yl + (int)cyi) * TX + (xl + (int)cxi);
    const uint4 n0 = t4[rho * 2], n1 = t4[rho * 2 + 1];
    float nv[KSEL];
    unpack9(n0, n1, nv);
    float s = 0.f;
    #pragma unroll
    for (int l = 0; l < KSEL; ++l) {
      const float t = ws[l] - nv[l] + 1e-6f;
      s = fmaf(t, t, s);
    }
    logit[j] = -s * inv;
  }

  // softmax over the 9 logits
  float mx = logit[0];
  #pragma unroll
  for (int j = 1; j < KSEL; ++j) mx = fmaxf(mx, logit[j]);
  float sum = 0.f;
  float e[KSEL];
  #pragma unroll
  for (int j = 0; j < KSEL; ++j) { e[j] = __expf(logit[j] - mx); sum += e[j]; }
  const float rs = 1.0f / sum;

  // ---- Reuse tile as output staging. ----
  __syncthreads();
  float* tf = (float*)tile;
  #pragma unroll
  for (int j = 0; j < KSEL; ++j) tf[tid * KSEL + j] = e[j] * rs;
  __syncthreads();

  // 8 y-rows x 72 float4; row r starts at voxel vb=(z,y0+r,x0).
  const float4* tf4 = (const float4*)tile;
  #pragma unroll
  for (int s = 0; s < 3; ++s) {
    const unsigned q = (unsigned)(s * 256 + tid);
    if (q < 576u) {
      const unsigned row = q / 72u;
      const unsigned f   = q - row * 72u;
      const unsigned vb  = (unsigned)((z << 14) | ((y0 + (int)row) << 7) | x0);
      ((float4*)out)[(size_t)(vb >> 2) * 9 + f] = tf4[row * 72 + f];
    }
  }
}

// ---------------------------------------------------------------------------
// d_in: [0] input (P floats), [1] ksigma (1 float), [2] k (int), [3] w (int)
// d_ws: fp16 row array, P * 8 dwords = 32 MB
// ---------------------------------------------------------------------------
extern "C" void kernel_launch(void* const* d_in, const int* in_sizes, int n_in,
                              void* d_out, int out_size, void* d_ws, size_t ws_size,
                              hipStream_t stream) {
  const float* anat = (const float*)d_in[0];
  const float* ksig = (const float*)d_in[1];
  unsigned* rows = (unsigned*)d_ws;

  const int blocks = P / 256;
  topk6<<<blocks, 256, 0, stream>>>(anat, rows);
  weights6<<<blocks, 256, 0, stream>>>(rows, ksig, (float*)d_out);
}

// Round 8
// 129.621 us; speedup vs baseline: 1.0899x; 1.0111x over previous
//
#include <hip/hip_runtime.h>
#include <hip/hip_fp16.h>
#include <array>

// Problem constants (reference: H=64, M=N=128, k=9, w=3)
constexpr int HZ   = 64;
constexpr int NN   = 128;
constexpr int P    = HZ * NN * NN;    // 1,048,576 voxels
constexpr int KSEL = 9;
constexpr int NCOL = 27;              // 3x3x3 window
// fp16 row layout, 8 dwords (32 B): d0=h0h1 d1=h2h3 d2=h4h5 d3=h6h7
// d4=h8 (hi16=0) d5=code_lo(6x5b) d6=code_hi(3x5b) d7=pad
constexpr int STD  = 8;               // row stride in dwords

typedef _Float16 f16x2 __attribute__((ext_vector_type(2)));

// Shared tiling for BOTH kernels: 8y x 32x core per block, swizzled so each
// XCD owns a contiguous 8-z slab -> topk's row writes land in the same XCD L2
// that weights reads from.
constexpr int TY = 10;   // 8 core + 2 halo
constexpr int TX = 34;   // 32 core + 2 halo

// ---------------------------------------------------------------------------
// Batcher merge-exchange network for n=27 (Knuth 5.2.2M) + backward dead-CE
// pruning to outputs 0..8.
// ---------------------------------------------------------------------------
constexpr int compute_nce(int n) {
  int t = 0; while ((1 << t) < n) ++t;
  int cnt = 0;
  for (int p = 1 << (t - 1); p > 0; p >>= 1) {
    int q = 1 << (t - 1), r = 0, d = p;
    while (true) {
      for (int i = 0; i < n - d; ++i)
        if ((i & p) == r) ++cnt;
      if (q == p) break;
      d = q - p; r = p; q >>= 1;
    }
  }
  return cnt;
}
constexpr int NCE_FULL = compute_nce(NCOL);   // 155

struct CEPair { unsigned char a, b; };
constexpr std::array<CEPair, NCE_FULL> make_net() {
  std::array<CEPair, NCE_FULL> net{};
  int t = 0; while ((1 << t) < NCOL) ++t;
  int k = 0;
  for (int p = 1 << (t - 1); p > 0; p >>= 1) {
    int q = 1 << (t - 1), r = 0, d = p;
    while (true) {
      for (int i = 0; i < NCOL - d; ++i)
        if ((i & p) == r) {
          net[k].a = (unsigned char)i;
          net[k].b = (unsigned char)(i + d);
          ++k;
        }
      if (q == p) break;
      d = q - p; r = p; q >>= 1;
    }
  }
  return net;
}
constexpr auto FULLNET = make_net();

constexpr int count_pruned() {
  bool needed[NCOL] = {};
  for (int i = 0; i < KSEL; ++i) needed[i] = true;
  int cnt = 0;
  for (int e = NCE_FULL - 1; e >= 0; --e) {
    const int a = FULLNET[e].a, b = FULLNET[e].b;
    if (needed[a] || needed[b]) { needed[a] = true; needed[b] = true; ++cnt; }
  }
  return cnt;
}
constexpr int NCE = count_pruned();

constexpr std::array<CEPair, NCE> make_pruned() {
  bool needed[NCOL] = {};
  for (int i = 0; i < KSEL; ++i) needed[i] = true;
  std::array<bool, NCE_FULL> keep{};
  for (int e = NCE_FULL - 1; e >= 0; --e) {
    const int a = FULLNET[e].a, b = FULLNET[e].b;
    if (needed[a] || needed[b]) { keep[e] = true; needed[a] = true; needed[b] = true; }
  }
  std::array<CEPair, NCE> out{};
  int k = 0;
  for (int e = 0; e < NCE_FULL; ++e) if (keep[e]) out[k++] = FULLNET[e];
  return out;
}
constexpr auto NET = make_pruned();

// ---------------------------------------------------------------------------
// Pass 1 (R8): same sort as R7 (u64 keys: db<<33 | col<<28 | vbits>>4, exact
// stable order), re-tiled to the weights tiling (8y x 32x core + same XCD
// swizzle) for producer/consumer L2 affinity. 27 gather reads become
// ds_read_b32 with compile-time immediate offsets.
// ---------------------------------------------------------------------------
__global__ __launch_bounds__(256) void topk7(
    const float* __restrict__ anat,
    unsigned* __restrict__ rows) {
  __shared__ float in_t[3 * TY * TX];   // 1020 floats = 4.08 KB input halo
  __shared__ unsigned lrow[256 * STD];  // 8 KB output staging
  const int tid = threadIdx.x;

  const int blk = blockIdx.x;
  const int swz = ((blk & 7) << 9) | (blk >> 3);   // 8 XCDs x 512-slab
  const int z    = swz >> 6;
  const int rest = swz & 63;
  const int y0   = ((rest >> 2) & 15) << 3;
  const int x0   = (rest & 3) << 5;
  const int xl   = tid & 31;
  const int yl   = tid >> 5;            // 0..7

  // Stage input halo: 3z x 10y x 34x floats.
  #pragma unroll
  for (int s = 0; s < 4; ++s) {
    const unsigned q = (unsigned)(s * 256 + tid);
    if (q < (unsigned)(3 * TY * TX)) {
      const unsigned p = q / TX;          // (zi,yi) 0..29
      const unsigned r = q - p * TX;      // x 0..33
      const unsigned pz = p / TY;
      const int zi = (int)pz, yi = (int)(p - TY * pz);
      const int zz = (z + zi - 1) & (HZ - 1);
      const int yy = (y0 + yi - 1) & (NN - 1);
      const int xg = (x0 - 1 + (int)r) & (NN - 1);
      in_t[q] = anat[(zz << 14) | (yy << 7) | xg];
    }
  }
  __syncthreads();

  const int base = (yl * TX) + xl;       // zi=0,yi=yl,xt=xl corner
  const float center = in_t[base + 1 * (TY * TX) + 1 * TX + 1];

  unsigned long long key[NCOL];
  #pragma unroll
  for (int c = 0; c < NCOL; ++c) {
    const int czi = c / 9, cyi = (c / 3) % 3, cxi = c % 3;
    const float v = in_t[base + czi * (TY * TX) + cyi * TX + cxi]; // const offs
    const unsigned vb = __float_as_uint(v);
    const unsigned db = __float_as_uint(v - center) & 0x7fffffffu;
    const unsigned hi32 = (db << 1) | ((unsigned)c >> 4);
    const unsigned lo32 = ((unsigned)c << 28) | (vb >> 4);
    key[c] = ((unsigned long long)hi32 << 32) | lo32;
  }

  // Pruned sorting network (u64 CEs).
  #pragma unroll
  for (int e = 0; e < NCE; ++e) {
    const int a = NET[e].a, b = NET[e].b;
    const unsigned long long xk = key[a], yk = key[b];
    const bool sw = xk > yk;
    key[a] = sw ? yk : xk;
    key[b] = sw ? xk : yk;
  }

  // Epilogue: extract col + value (top-28 bits), pack fp16 row + codes.
  unsigned d[5] = {0, 0, 0, 0, 0};
  unsigned lo = 0, hi = 0;
  #pragma unroll
  for (int s = 0; s < KSEL; ++s) {
    const unsigned c  = (unsigned)(key[s] >> 28) & 31u;
    const unsigned vb = ((unsigned)key[s] & 0x0fffffffu) << 4;
    const ushort hb = __half_as_ushort(__float2half(__uint_as_float(vb)));
    d[s >> 1] |= (unsigned)hb << ((s & 1) * 16);
    if (s < 6) lo |= c << (5 * s);
    else       hi |= c << (5 * (s - 6));
  }

  unsigned* myrow = &lrow[tid * STD];
  ((uint4*)myrow)[0] = make_uint4(d[0], d[1], d[2], d[3]);
  ((uint4*)myrow)[1] = make_uint4(d[4], lo, hi, 0u);

  __syncthreads();

  // Writeback: 8 y-runs, each 32 contiguous rows = 64 uint4 (1 KB, coalesced).
  uint4* rows4 = (uint4*)rows;
  const uint4* l4 = (const uint4*)lrow;
  #pragma unroll
  for (int s = 0; s < 2; ++s) {
    const unsigned q   = (unsigned)(s * 256 + tid);
    const unsigned run = q >> 6;          // y-row 0..7
    const unsigned off = q & 63u;
    const unsigned vb  = (unsigned)((z << 14) | ((y0 + (int)run) << 7) | x0);
    rows4[(size_t)vb * 2 + off] = l4[run * 64 + off];
  }
}

// ---------------------------------------------------------------------------
// Pass 2 (R8): staging identical to R7; distance math in packed f16:
// 5x pk_sub + 5x pk_add + 5x v_dot2_f32_f16 per neighbor (was ~36 VALU).
// eps=1e-6 is sub-ulp at these magnitudes in BOTH f16 and the fp32 reference;
// the pad lane contributes eps^2 ~ 1e-12 (negligible).
// ---------------------------------------------------------------------------
constexpr int TROWS = 3 * TY * TX;   // 1020

__global__ __launch_bounds__(256) void weights7(
    const unsigned* __restrict__ rows,
    const float* __restrict__ ksig,
    float* __restrict__ out) {
  __shared__ unsigned tile[TROWS * STD];   // 32640 B; reused for out staging
  const int tid = threadIdx.x;

  const int blk = blockIdx.x;
  const int swz = ((blk & 7) << 9) | (blk >> 3);
  const int z    = swz >> 6;
  const int rest = swz & 63;
  const int y0   = ((rest >> 2) & 15) << 3;
  const int x0   = (rest & 3) << 5;
  const int xl   = tid & 31;
  const int yl   = tid >> 5;

  // ---- Stage halo: 1020 rows x 2 uint4 = 2040 uint4 (8/thread). ----
  const uint4* rows4 = (const uint4*)rows;
  uint4* t4 = (uint4*)tile;
  #pragma unroll
  for (int s = 0; s < 8; ++s) {
    const unsigned q = (unsigned)(s * 256 + tid);
    if (q < 2040u) {
      const unsigned p   = q / 68u;        // (zi,yi) pair 0..29
      const unsigned rem = q - p * 68u;
      const unsigned r   = rem >> 1;       // x-row 0..33
      const unsigned c   = rem & 1u;
      const unsigned pz  = p / 10u;
      const int zi = (int)pz, yi = (int)(p - 10u * pz);
      const int zz = (z + zi - 1) & (HZ - 1);
      const int yy = (y0 + yi - 1) & (NN - 1);
      const int xg = (x0 - 1 + (int)r) & (NN - 1);
      t4[q] = rows4[(size_t)((zz << 14) | (yy << 7) | xg) * 2 + c];
    }
  }
  __syncthreads();

  // ---- Own row: zi=1, yi=yl+1, xt=xl+1. ----
  const int rho_own = (TY + (yl + 1)) * TX + (xl + 1);
  const uint4 u0 = t4[rho_own * 2], u1 = t4[rho_own * 2 + 1];
  f16x2 wh[5];
  wh[0] = __builtin_bit_cast(f16x2, u0.x);
  wh[1] = __builtin_bit_cast(f16x2, u0.y);
  wh[2] = __builtin_bit_cast(f16x2, u0.z);
  wh[3] = __builtin_bit_cast(f16x2, u0.w);
  wh[4] = __builtin_bit_cast(f16x2, u1.x);   // hi lane = 0
  const unsigned lo = u1.y;
  const unsigned hi = u1.z;

  // sigma with ddof=1 (two-pass, matches jnp.std) on f32-widened values.
  float ws[KSEL];
  #pragma unroll
  for (int l = 0; l < KSEL; ++l) ws[l] = (float)wh[l >> 1][l & 1];
  float mean = 0.f;
  #pragma unroll
  for (int l = 0; l < KSEL; ++l) mean += ws[l];
  mean *= (1.0f / 9.0f);
  float var = 0.f;
  #pragma unroll
  for (int l = 0; l < KSEL; ++l) { const float t = ws[l] - mean; var += t * t; }
  var *= (1.0f / 8.0f);
  const float sigma = sqrtf(var);

  const float ks = ksig[0];
  const float inv = (sigma == 0.f) ? 0.f : 1.0f / (2.0f * ks * ks * sigma * sigma);

  const _Float16 epsh = (_Float16)1e-6f;
  const f16x2 eps2 = {epsh, epsh};

  float logit[KSEL];
  #pragma unroll
  for (int j = 0; j < KSEL; ++j) {
    const unsigned c = (j < 6) ? ((lo >> (5 * j)) & 31u)
                               : ((hi >> (5 * (j - 6))) & 31u);
    const unsigned czi = (c * 57u) >> 9;          // c / 9
    const unsigned rem = c - 9u * czi;
    const unsigned cyi = (rem * 11u) >> 5;        // rem / 3
    const unsigned cxi = rem - 3u * cyi;
    const int rho = (int)czi * (TY * TX) + (yl + (int)cyi) * TX + (xl + (int)cxi);
    const uint4 n0 = t4[rho * 2], n1 = t4[rho * 2 + 1];
    float s = 0.f;
    const f16x2 nh0 = __builtin_bit_cast(f16x2, n0.x);
    const f16x2 nh1 = __builtin_bit_cast(f16x2, n0.y);
    const f16x2 nh2 = __builtin_bit_cast(f16x2, n0.z);
    const f16x2 nh3 = __builtin_bit_cast(f16x2, n0.w);
    const f16x2 nh4 = __builtin_bit_cast(f16x2, n1.x);
    f16x2 dd;
    dd = (wh[0] - nh0) + eps2; s = __builtin_amdgcn_fdot2(dd, dd, s, false);
    dd = (wh[1] - nh1) + eps2; s = __builtin_amdgcn_fdot2(dd, dd, s, false);
    dd = (wh[2] - nh2) + eps2; s = __builtin_amdgcn_fdot2(dd, dd, s, false);
    dd = (wh[3] - nh3) + eps2; s = __builtin_amdgcn_fdot2(dd, dd, s, false);
    dd = (wh[4] - nh4) + eps2; s = __builtin_amdgcn_fdot2(dd, dd, s, false);
    logit[j] = -s * inv;
  }

  // softmax over the 9 logits
  float mx = logit[0];
  #pragma unroll
  for (int j = 1; j < KSEL; ++j) mx = fmaxf(mx, logit[j]);
  float sum = 0.f;
  float e[KSEL];
  #pragma unroll
  for (int j = 0; j < KSEL; ++j) { e[j] = __expf(logit[j] - mx); sum += e[j]; }
  const float rs = 1.0f / sum;

  // ---- Reuse tile as output staging. ----
  __syncthreads();
  float* tf = (float*)tile;
  #pragma unroll
  for (int j = 0; j < KSEL; ++j) tf[tid * KSEL + j] = e[j] * rs;
  __syncthreads();

  // 8 y-rows x 72 float4; row r starts at voxel vb=(z,y0+r,x0).
  const float4* tf4 = (const float4*)tile;
  #pragma unroll
  for (int s = 0; s < 3; ++s) {
    const unsigned q = (unsigned)(s * 256 + tid);
    if (q < 576u) {
      const unsigned row = q / 72u;
      const unsigned f   = q - row * 72u;
      const unsigned vb  = (unsigned)((z << 14) | ((y0 + (int)row) << 7) | x0);
      ((float4*)out)[(size_t)(vb >> 2) * 9 + f] = tf4[row * 72 + f];
    }
  }
}

// ---------------------------------------------------------------------------
// d_in: [0] input (P floats), [1] ksigma (1 float), [2] k (int), [3] w (int)
// d_ws: fp16 row array, P * 8 dwords = 32 MB
// ---------------------------------------------------------------------------
extern "C" void kernel_launch(void* const* d_in, const int* in_sizes, int n_in,
                              void* d_out, int out_size, void* d_ws, size_t ws_size,
                              hipStream_t stream) {
  const float* anat = (const float*)d_in[0];
  const float* ksig = (const float*)d_in[1];
  unsigned* rows = (unsigned*)d_ws;

  const int blocks = P / 256;
  topk7<<<blocks, 256, 0, stream>>>(anat, rows);
  weights7<<<blocks, 256, 0, stream>>>(rows, ksig, (float*)d_out);
}